// Round 19
// baseline (109.043 us; speedup 1.0000x reference)
//
#include <hip/hip_runtime.h>

#define HEADS 4
#define BSHIFT 8          // 256 nodes per bucket; requires n < 65536 for (d<<16)|s packing

typedef __attribute__((ext_vector_type(8))) short bf16x8;
typedef __attribute__((ext_vector_type(4))) float f32x4;

__device__ __forceinline__ unsigned short f2bf(float f) {
  unsigned u = __builtin_bit_cast(unsigned, f);
  u = (u + 0x7FFFu + ((u >> 16) & 1u)) >> 16;
  return (unsigned short)u;
}
__device__ __forceinline__ unsigned pack_bf16x2(float a, float b) {
  unsigned ua = __builtin_bit_cast(unsigned, a);
  unsigned ub = __builtin_bit_cast(unsigned, b);
  ua = (ua + 0x7FFFu + ((ua >> 16) & 1u)) >> 16;
  ub = (ub + 0x7FFFu + ((ub >> 16) & 1u)) >> 16;
  return ua | (ub << 16);
}
__device__ __forceinline__ float bf_lo(unsigned u) {
  return __builtin_bit_cast(float, u << 16);
}
__device__ __forceinline__ float bf_hi(unsigned u) {
  return __builtin_bit_cast(float, u & 0xFFFF0000u);
}

// ---------------- k_prep: per-block hist partials (no atomics/zero-init) + W conversion ------
__global__ __launch_bounds__(256) void k_prep(
    const float* __restrict__ W, unsigned short* __restrict__ Wtb,
    const int* __restrict__ dste, int* __restrict__ phist, int E)
{
  const int t = threadIdx.x;
  if (blockIdx.x < 64) {
    const int i = blockIdx.x * 256 + t;   // c-major: coalesced writes
    const int c = i >> 7, k = i & 127;
    Wtb[i] = f2bf(W[k * 128 + c]);
  }
  __shared__ int h[256];
  h[t] = 0;
  __syncthreads();
  int i = blockIdx.x * 4096 + t;
#pragma unroll
  for (int k = 0; k < 16; ++k, i += 256)
    if (i < E) atomicAdd(&h[dste[i] >> BSHIFT], 1);
  __syncthreads();
  phist[blockIdx.x * 256 + t] = h[t];
}

// ---------------- k_scan: sum partials + exclusive bucket scan -> gstart/gcur ----------------
__global__ __launch_bounds__(256) void k_scan(
    const int* __restrict__ phist, int* __restrict__ gstart, int* __restrict__ gcur, int NHB)
{
  const int t = threadIdx.x;
  int v = 0;
  for (int b = 0; b < NHB; ++b) v += phist[b * 256 + t];
  __shared__ int wsum[4];
  const int lane = t & 63, w = t >> 6;
  int s = v;
#pragma unroll
  for (int o = 1; o < 64; o <<= 1) { int u = __shfl_up(s, o); if (lane >= o) s += u; }
  if (lane == 63) wsum[w] = s;
  __syncthreads();
  int add = 0;
  for (int k = 0; k < w; ++k) add += wsum[k];
  const int excl = add + s - v;
  gstart[t] = excl;
  gcur[t] = excl;
  if (t == 255) gstart[256] = excl + v;
}

// ---------------- k_mega3: blocks [0,NPB) = partition (FIRST, overlaps GEMM); rest = GEMM ----
__global__ __launch_bounds__(256) void k_mega3(
    const float* __restrict__ x, const unsigned short* __restrict__ Wtb,
    const float* __restrict__ att_src, const float* __restrict__ att_dst,
    unsigned* __restrict__ xpb, float* __restrict__ a_s, float* __restrict__ a_d,
    const int* __restrict__ srce, const int* __restrict__ dste,
    int* __restrict__ gcur, unsigned* __restrict__ pbuf,
    int n, int E, int NPB)
{
  __shared__ __align__(16) unsigned short xb[64 * 136];
  __shared__ __align__(16) unsigned short Wt[128 * 136];
  __shared__ float asl[128], adl[128];
  const int tid = threadIdx.x;

  if (blockIdx.x < NPB) {
    // ---------- partition path (LDS counting-sort by bucket, coalesced run-writes) ----------
    unsigned* sortbuf = (unsigned*)xb;          // 16 KB <= 17.4 KB
    int* hist   = (int*)Wt;                     // overlay: 1028 ints <= 34.8 KB
    int* lstart = hist + 256;
    int* lcur   = hist + 512;
    int* wbase  = hist + 768;
    int* wsumP  = hist + 1024;
    const int e0 = blockIdx.x * 4096;
    const int cnt = min(4096, E - e0);
    hist[tid] = 0;
    __syncthreads();
    for (int i = tid; i < cnt; i += 256)
      atomicAdd(&hist[dste[e0 + i] >> BSHIFT], 1);
    __syncthreads();
    const int lane = tid & 63, w = tid >> 6;
    const int v = hist[tid];
    int s = v;
#pragma unroll
    for (int o = 1; o < 64; o <<= 1) { int u = __shfl_up(s, o); if (lane >= o) s += u; }
    if (lane == 63) wsumP[w] = s;
    __syncthreads();
    int add = 0;
    for (int k = 0; k < w; ++k) add += wsumP[k];
    const int ls = add + s - v;
    lstart[tid] = ls;
    lcur[tid] = ls;
    wbase[tid] = (v > 0) ? atomicAdd(&gcur[tid], v) : 0;
    __syncthreads();
    for (int i = tid; i < cnt; i += 256) {
      const int d = dste[e0 + i], sE = srce[e0 + i];
      const int r = atomicAdd(&lcur[d >> BSHIFT], 1);
      sortbuf[r] = ((unsigned)d << 16) | (unsigned)sE;
    }
    __syncthreads();
    for (int i = tid; i < cnt; i += 256) {
      const unsigned p = sortbuf[i];
      const int b = (int)(p >> (16 + BSHIFT));
      pbuf[wbase[b] + (i - lstart[b])] = p;
    }
    return;
  }

  // ---------- GEMM path ----------
  const int row0 = (blockIdx.x - NPB) * 64;
  if (tid < 128) { asl[tid] = att_src[tid]; adl[tid] = att_dst[tid]; }

  // stage x tile (64x128) as bf16, packed uint2 writes
  for (int u = tid; u < 2048; u += 256) {
    const int r = u >> 5, cq = u & 31;
    float4 v = make_float4(0.f, 0.f, 0.f, 0.f);
    if (row0 + r < n) v = ((const float4*)x)[(size_t)(row0 + r) * 32 + cq];
    uint2 pw;
    pw.x = pack_bf16x2(v.x, v.y);
    pw.y = pack_bf16x2(v.z, v.w);
    *(uint2*)&xb[r * 136 + cq * 4] = pw;
  }
  for (int u = tid; u < 2048; u += 256) {
    const int c = u >> 4, q = u & 15;
    *(uint4*)&Wt[c * 136 + q * 8] = ((const uint4*)Wtb)[u];
  }
  __syncthreads();

  const int wv = tid >> 6;
  const int lane = tid & 63;
  const int r = lane & 15, g = lane >> 4;

  f32x4 acc[8];
#pragma unroll
  for (int t = 0; t < 8; ++t) acc[t] = (f32x4){0.f, 0.f, 0.f, 0.f};

  bf16x8 afr[4];
#pragma unroll
  for (int kc = 0; kc < 4; ++kc)
    afr[kc] = *(const bf16x8*)&xb[(16 * wv + r) * 136 + kc * 32 + g * 8];

#pragma unroll
  for (int kc = 0; kc < 4; ++kc) {
#pragma unroll
    for (int t = 0; t < 8; ++t) {
      const bf16x8 bfr = *(const bf16x8*)&Wt[(16 * t + r) * 136 + kc * 32 + g * 8];
      acc[t] = __builtin_amdgcn_mfma_f32_16x16x32_bf16(afr[kc], bfr, acc[t], 0, 0, 0);
    }
  }
  __syncthreads();   // done reading xb/Wt

  // D fragments -> obuf bf16 (overlay Wt), rows padded to 136 (16B-aligned rows)
  unsigned short* obuf = Wt;
#pragma unroll
  for (int t = 0; t < 8; ++t) {
#pragma unroll
    for (int j = 0; j < 4; ++j)
      obuf[(16 * wv + 4 * g + j) * 136 + 16 * t + r] = f2bf(acc[t][j]);
  }
  __syncthreads();

  // per-(row,head) logits, vectorized: uint4 obuf reads + float4 att reads from LDS
  {
    const int row = tid >> 2, h = tid & 3;
    float ps = 0.f, pd = 0.f;
    const unsigned short* orow = &obuf[row * 136 + 32 * h];
#pragma unroll
    for (int jj = 0; jj < 4; ++jj) {
      const uint4 v8 = *(const uint4*)&orow[jj * 8];
      const float4 s0 = *(const float4*)&asl[32 * h + jj * 8];
      const float4 s1 = *(const float4*)&asl[32 * h + jj * 8 + 4];
      const float4 d0 = *(const float4*)&adl[32 * h + jj * 8];
      const float4 d1 = *(const float4*)&adl[32 * h + jj * 8 + 4];
      ps += bf_lo(v8.x) * s0.x + bf_hi(v8.x) * s0.y + bf_lo(v8.y) * s0.z + bf_hi(v8.y) * s0.w
          + bf_lo(v8.z) * s1.x + bf_hi(v8.z) * s1.y + bf_lo(v8.w) * s1.z + bf_hi(v8.w) * s1.w;
      pd += bf_lo(v8.x) * d0.x + bf_hi(v8.x) * d0.y + bf_lo(v8.y) * d0.z + bf_hi(v8.y) * d0.w
          + bf_lo(v8.z) * d1.x + bf_hi(v8.z) * d1.y + bf_lo(v8.w) * d1.z + bf_hi(v8.w) * d1.w;
    }
    if (row0 + row < n) {
      a_s[(row0 + row) * HEADS + h] = ps;
      a_d[(row0 + row) * HEADS + h] = pd;
    }
  }
  // copy out xpb rows (uint2 = 4 bf16)
  for (int u = tid; u < 2048; u += 256) {
    const int row = u >> 5, q = u & 31;
    if (row0 + row < n)
      ((uint2*)xpb)[(size_t)(row0 + row) * 32 + q] = *(const uint2*)&obuf[row * 136 + q * 4];
  }
}

// ---------------- k_fill2: per-node offs + edge placement (bucket-local writes) -------------
__global__ __launch_bounds__(256) void k_fill2(
    const unsigned* __restrict__ pbuf, const int* __restrict__ gstart,
    int* __restrict__ offs, int* __restrict__ eidx, int n, int E)
{
  __shared__ int cnt[256], base[256];
  __shared__ int wsum[4];
  const int b = blockIdx.x, t = threadIdx.x;
  const int node0 = b << BSHIFT;
  const int ebeg = gstart[b], eend = gstart[b + 1];
  cnt[t] = 0;
  __syncthreads();
  for (int i = ebeg + t; i < eend; i += 256)
    atomicAdd(&cnt[(pbuf[i] >> 16) & 255], 1);
  __syncthreads();
  const int lane = t & 63, w = t >> 6;
  const int v = cnt[t];
  int s = v;
#pragma unroll
  for (int o = 1; o < 64; o <<= 1) { int u = __shfl_up(s, o); if (lane >= o) s += u; }
  if (lane == 63) wsum[w] = s;
  __syncthreads();
  int add = 0;
  for (int k = 0; k < w; ++k) add += wsum[k];
  base[t] = ebeg + add + s - v;
  if (node0 + t < n) offs[node0 + t] = base[t];
  __syncthreads();
  for (int i = ebeg + t; i < eend; i += 256) {
    const unsigned p = pbuf[i];
    const int pos = atomicAdd(&base[(p >> 16) & 255], 1);
    eidx[pos] = (int)(p & 0xFFFFu);
  }
  if (b == 0 && t == 0) offs[n] = E;
}

// ---------------- Aggregation: one wave per dst node (proven version) -----------------------
__global__ __launch_bounds__(256) void k_aggr(
    const unsigned* __restrict__ xpb, const float* __restrict__ a_s,
    const float* __restrict__ a_d, const int* __restrict__ offs,
    const int* __restrict__ eidx, const float* __restrict__ bias,
    float* __restrict__ out, int n)
{
  const int wid = (blockIdx.x * blockDim.x + threadIdx.x) >> 6;
  const int lane = threadIdx.x & 63;
  if (wid >= n) return;
  const int h = lane >> 4;
  const int sbase = lane & 48;

  const float adh = a_d[wid * HEADS + h];

  float l = a_s[wid * HEADS + h] + adh;
  l = fmaxf(l, 0.2f * l);
  const float pself = __expf(l);
  float den = pself;
  const unsigned uself = xpb[(size_t)wid * 64 + lane];
  float accx = pself * bf_lo(uself), accy = pself * bf_hi(uself);

  const int beg = offs[wid], end = offs[wid + 1];
  int e = beg;
  int nb = (end - beg) >> 2;

#define LOADB(s0, s1, s2, s3, u0, u1, u2, u3, aL)                        \
  {                                                                      \
    s0 = eidx[e]; s1 = eidx[e + 1]; s2 = eidx[e + 2]; s3 = eidx[e + 3];  \
    u0 = xpb[(size_t)s0 * 64 + lane];                                    \
    u1 = xpb[(size_t)s1 * 64 + lane];                                    \
    u2 = xpb[(size_t)s2 * 64 + lane];                                    \
    u3 = xpb[(size_t)s3 * 64 + lane];                                    \
    const int sj = (lane & 2) ? ((lane & 1) ? s3 : s2)                   \
                              : ((lane & 1) ? s1 : s0);                  \
    aL = a_s[sj * HEADS + h];                                            \
  }
#define CONSUME(u0, u1, u2, u3, aL)                                      \
  {                                                                      \
    float lv = aL + adh; lv = fmaxf(lv, 0.2f * lv);                      \
    const float pl = __expf(lv);                                         \
    const float p0 = __shfl(pl, sbase + 0);                              \
    const float p1 = __shfl(pl, sbase + 1);                              \
    const float p2 = __shfl(pl, sbase + 2);                              \
    const float p3 = __shfl(pl, sbase + 3);                              \
    den += p0 + p1 + p2 + p3;                                            \
    accx += p0 * bf_lo(u0) + p1 * bf_lo(u1) + p2 * bf_lo(u2) + p3 * bf_lo(u3); \
    accy += p0 * bf_hi(u0) + p1 * bf_hi(u1) + p2 * bf_hi(u2) + p3 * bf_hi(u3); \
  }

  if (nb > 0) {
    int sa0, sa1, sa2, sa3, sb0, sb1, sb2, sb3;
    unsigned ua0, ua1, ua2, ua3, ub0, ub1, ub2, ub3;
    float aa, ab;
    LOADB(sa0, sa1, sa2, sa3, ua0, ua1, ua2, ua3, aa);
    e += 4;
    --nb;
    while (nb >= 2) {
      LOADB(sb0, sb1, sb2, sb3, ub0, ub1, ub2, ub3, ab);
      e += 4;
      CONSUME(ua0, ua1, ua2, ua3, aa);
      LOADB(sa0, sa1, sa2, sa3, ua0, ua1, ua2, ua3, aa);
      e += 4;
      CONSUME(ub0, ub1, ub2, ub3, ab);
      nb -= 2;
    }
    if (nb == 1) {
      LOADB(sb0, sb1, sb2, sb3, ub0, ub1, ub2, ub3, ab);
      e += 4;
      CONSUME(ua0, ua1, ua2, ua3, aa);
      CONSUME(ub0, ub1, ub2, ub3, ab);
    } else {
      CONSUME(ua0, ua1, ua2, ua3, aa);
    }
  }
  for (; e < end; ++e) {
    const int s = eidx[e];
    const unsigned u = xpb[(size_t)s * 64 + lane];
    float lv = a_s[s * HEADS + h] + adh;
    lv = fmaxf(lv, 0.2f * lv);
    const float p = __expf(lv);
    den += p;
    accx += p * bf_lo(u);
    accy += p * bf_hi(u);
  }
#undef LOADB
#undef CONSUME

  const float2 b2 = ((const float2*)bias)[lane];
  const float inv = 1.f / den;
  float ox = accx * inv + b2.x;
  float oy = accy * inv + b2.y;
  float2 o = make_float2(ox > 0.f ? ox : 0.f, oy > 0.f ? oy : 0.f);
  ((float2*)out)[(size_t)wid * 64 + lane] = o;
}

extern "C" void kernel_launch(void* const* d_in, const int* in_sizes, int n_in,
                              void* d_out, int out_size, void* d_ws, size_t ws_size,
                              hipStream_t stream) {
  const float* x       = (const float*)d_in[0];
  const int*   ei      = (const int*)d_in[1];
  const float* W       = (const float*)d_in[2];
  const float* att_src = (const float*)d_in[3];
  const float* att_dst = (const float*)d_in[4];
  const float* bias    = (const float*)d_in[5];
  float* out = (float*)d_out;
  const int n = in_sizes[0] / 128;
  const int E = in_sizes[1] / 2;
  const int* srce = ei;
  const int* dste = ei + E;

  const int GB  = (n + 63) / 64;          // GEMM blocks (782)
  const int NPB = (E + 4095) / 4096;      // hist/part blocks (196, >= 64 for W slice)
  const int NB  = (n + 255) >> BSHIFT;    // buckets (196)

  char* ws = (char*)d_ws;
  size_t o = 0;
  unsigned* xpb = (unsigned*)(ws + o); o += (size_t)n * 128 * 2;  // bf16 xp
  o = (o + 255) & ~(size_t)255;
  float* a_s = (float*)(ws + o); o += (size_t)n * HEADS * 4;
  float* a_d = (float*)(ws + o); o += (size_t)n * HEADS * 4;
  unsigned short* Wtb = (unsigned short*)(ws + o); o += 128 * 128 * 2;
  int* phist  = (int*)(ws + o);  o += (size_t)NPB * 256 * 4;
  int* gstart = (int*)(ws + o);  o += 260 * 4;
  int* gcur   = (int*)(ws + o);  o += 256 * 4;
  int* offs   = (int*)(ws + o);  o += (size_t)(n + 4) * 4;
  int* eidx   = (int*)(ws + o);  o += (size_t)E * 4;
  unsigned* pbuf = (unsigned*)(ws + o); o += (size_t)E * 4;

  k_prep<<<NPB, 256, 0, stream>>>(W, Wtb, dste, phist, E);
  k_scan<<<1, 256, 0, stream>>>(phist, gstart, gcur, NPB);
  k_mega3<<<NPB + GB, 256, 0, stream>>>(x, Wtb, att_src, att_dst, xpb, a_s, a_d,
                                        srce, dste, gcur, pbuf, n, E, NPB);
  k_fill2<<<NB, 256, 0, stream>>>(pbuf, gstart, offs, eidx, n, E);
  k_aggr<<<(n + 3) / 4, 256, 0, stream>>>(xpb, a_s, a_d, offs, eidx, bias, out, n);
}

// Round 20
// 104.844 us; speedup vs baseline: 1.0401x; 1.0401x over previous
//
#include <hip/hip_runtime.h>

#define HEADS 4
#define BSHIFT 8          // 256 nodes per bucket; requires n < 65536 for (d<<16)|s packing

typedef __attribute__((ext_vector_type(8))) short bf16x8;
typedef __attribute__((ext_vector_type(4))) float f32x4;

__device__ __forceinline__ unsigned short f2bf(float f) {
  unsigned u = __builtin_bit_cast(unsigned, f);
  u = (u + 0x7FFFu + ((u >> 16) & 1u)) >> 16;
  return (unsigned short)u;
}
__device__ __forceinline__ unsigned pack_bf16x2(float a, float b) {
  unsigned ua = __builtin_bit_cast(unsigned, a);
  unsigned ub = __builtin_bit_cast(unsigned, b);
  ua = (ua + 0x7FFFu + ((ua >> 16) & 1u)) >> 16;
  ub = (ub + 0x7FFFu + ((ub >> 16) & 1u)) >> 16;
  return ua | (ub << 16);
}
__device__ __forceinline__ float bf_lo(unsigned u) {
  return __builtin_bit_cast(float, u << 16);
}
__device__ __forceinline__ float bf_hi(unsigned u) {
  return __builtin_bit_cast(float, u & 0xFFFF0000u);
}

// ---------------- W prep: Wtb[c][k] = bf16(W[k][c]); block 0 zeroes ghist/done ----------------
__global__ __launch_bounds__(256) void k_wprep(
    const float* __restrict__ W, unsigned short* __restrict__ Wtb,
    int* __restrict__ ghist, int* __restrict__ done)
{
  const int i = blockIdx.x * 256 + threadIdx.x;   // c-major: coalesced writes
  const int c = i >> 7, k = i & 127;
  Wtb[i] = f2bf(W[k * 128 + c]);
  if (blockIdx.x == 0) {
    ghist[threadIdx.x] = 0;
    if (threadIdx.x == 0) *done = 0;
  }
}

// ---------------- Mega-kernel: blocks [0,GB) = MFMA GEMM; blocks [GB,GB+NHB) = hist(+scan) ----
__global__ __launch_bounds__(256) void k_mega(
    const float* __restrict__ x, const unsigned short* __restrict__ Wtb,
    const float* __restrict__ att_src, const float* __restrict__ att_dst,
    unsigned* __restrict__ xpb, float* __restrict__ a_s, float* __restrict__ a_d,
    const int* __restrict__ dste, int* __restrict__ ghist, int* __restrict__ gstart,
    int* __restrict__ gcur, int* __restrict__ done,
    int n, int E, int GB, int NHB)
{
  __shared__ __align__(16) unsigned short xb[64 * 136];
  __shared__ __align__(16) unsigned short Wt[128 * 136];
  __shared__ float asl[128], adl[128];
  const int tid = threadIdx.x;

  if (blockIdx.x >= GB) {
    // ---------- histogram path ----------
    int* h = (int*)xb;
    h[tid] = 0;
    __syncthreads();
    int i = (blockIdx.x - GB) * 4096 + tid;
#pragma unroll
    for (int k = 0; k < 16; ++k, i += 256)
      if (i < E) atomicAdd(&h[dste[i] >> BSHIFT], 1);
    __syncthreads();
    if (h[tid]) atomicAdd(&ghist[tid], h[tid]);
    __threadfence();
    __shared__ int lastFlag;
    if (tid == 0) lastFlag = (atomicAdd(done, 1) == NHB - 1) ? 1 : 0;
    __syncthreads();
    if (lastFlag) {
      __shared__ int wsum[4];
      const int lane = tid & 63, w = tid >> 6;
      const int v = atomicAdd(&ghist[tid], 0);   // coherent read
      int s = v;
#pragma unroll
      for (int o = 1; o < 64; o <<= 1) { int u = __shfl_up(s, o); if (lane >= o) s += u; }
      if (lane == 63) wsum[w] = s;
      __syncthreads();
      int add = 0;
      for (int k = 0; k < w; ++k) add += wsum[k];
      const int excl = add + s - v;
      gstart[tid] = excl;
      gcur[tid] = excl;
      if (tid == 255) gstart[256] = excl + v;
    }
    return;
  }

  // ---------- GEMM path ----------
  const int row0 = blockIdx.x * 64;
  if (tid < 128) { asl[tid] = att_src[tid]; adl[tid] = att_dst[tid]; }

  // stage x tile (64x128) as bf16, packed uint2 writes
  for (int u = tid; u < 2048; u += 256) {
    const int r = u >> 5, cq = u & 31;
    float4 v = make_float4(0.f, 0.f, 0.f, 0.f);
    if (row0 + r < n) v = ((const float4*)x)[(size_t)(row0 + r) * 32 + cq];
    uint2 pw;
    pw.x = pack_bf16x2(v.x, v.y);
    pw.y = pack_bf16x2(v.z, v.w);
    *(uint2*)&xb[r * 136 + cq * 4] = pw;
  }
  for (int u = tid; u < 2048; u += 256) {
    const int c = u >> 4, q = u & 15;
    *(uint4*)&Wt[c * 136 + q * 8] = ((const uint4*)Wtb)[u];
  }
  __syncthreads();

  const int wv = tid >> 6;
  const int lane = tid & 63;
  const int r = lane & 15, g = lane >> 4;

  f32x4 acc[8];
#pragma unroll
  for (int t = 0; t < 8; ++t) acc[t] = (f32x4){0.f, 0.f, 0.f, 0.f};

  bf16x8 afr[4];
#pragma unroll
  for (int kc = 0; kc < 4; ++kc)
    afr[kc] = *(const bf16x8*)&xb[(16 * wv + r) * 136 + kc * 32 + g * 8];

#pragma unroll
  for (int kc = 0; kc < 4; ++kc) {
#pragma unroll
    for (int t = 0; t < 8; ++t) {
      const bf16x8 bfr = *(const bf16x8*)&Wt[(16 * t + r) * 136 + kc * 32 + g * 8];
      acc[t] = __builtin_amdgcn_mfma_f32_16x16x32_bf16(afr[kc], bfr, acc[t], 0, 0, 0);
    }
  }
  __syncthreads();   // done reading xb/Wt

  // D fragments -> obuf bf16 (overlay Wt), rows padded to 136 (16B-aligned rows)
  unsigned short* obuf = Wt;
#pragma unroll
  for (int t = 0; t < 8; ++t) {
#pragma unroll
    for (int j = 0; j < 4; ++j)
      obuf[(16 * wv + 4 * g + j) * 136 + 16 * t + r] = f2bf(acc[t][j]);
  }
  __syncthreads();

  // per-(row,head) logits, vectorized: uint4 obuf reads + float4 att reads from LDS
  {
    const int row = tid >> 2, h = tid & 3;
    float ps = 0.f, pd = 0.f;
    const unsigned short* orow = &obuf[row * 136 + 32 * h];
#pragma unroll
    for (int jj = 0; jj < 4; ++jj) {
      const uint4 v8 = *(const uint4*)&orow[jj * 8];
      const float4 s0 = *(const float4*)&asl[32 * h + jj * 8];
      const float4 s1 = *(const float4*)&asl[32 * h + jj * 8 + 4];
      const float4 d0 = *(const float4*)&adl[32 * h + jj * 8];
      const float4 d1 = *(const float4*)&adl[32 * h + jj * 8 + 4];
      ps += bf_lo(v8.x) * s0.x + bf_hi(v8.x) * s0.y + bf_lo(v8.y) * s0.z + bf_hi(v8.y) * s0.w
          + bf_lo(v8.z) * s1.x + bf_hi(v8.z) * s1.y + bf_lo(v8.w) * s1.z + bf_hi(v8.w) * s1.w;
      pd += bf_lo(v8.x) * d0.x + bf_hi(v8.x) * d0.y + bf_lo(v8.y) * d0.z + bf_hi(v8.y) * d0.w
          + bf_lo(v8.z) * d1.x + bf_hi(v8.z) * d1.y + bf_lo(v8.w) * d1.z + bf_hi(v8.w) * d1.w;
    }
    if (row0 + row < n) {
      a_s[(row0 + row) * HEADS + h] = ps;
      a_d[(row0 + row) * HEADS + h] = pd;
    }
  }
  // copy out xpb rows (uint2 = 4 bf16)
  for (int u = tid; u < 2048; u += 256) {
    const int row = u >> 5, q = u & 31;
    if (row0 + row < n)
      ((uint2*)xpb)[(size_t)(row0 + row) * 32 + q] = *(const uint2*)&obuf[row * 136 + q * 4];
  }
}

// ---------------- k_part: LDS counting-sort by bucket, coalesced run-writes ----------------
__global__ __launch_bounds__(256) void k_part(
    const int* __restrict__ src, const int* __restrict__ dst,
    int* __restrict__ gcur, unsigned* __restrict__ pbuf, int E)
{
  __shared__ unsigned sortbuf[4096];
  __shared__ int hist[256], lstart[256], lcur[256], wbase[256];
  __shared__ int wsum[4];
  const int t = threadIdx.x;
  const int e0 = blockIdx.x * 4096;
  const int cnt = min(4096, E - e0);
  hist[t] = 0;
  __syncthreads();
  for (int i = t; i < cnt; i += 256)
    atomicAdd(&hist[dst[e0 + i] >> BSHIFT], 1);
  __syncthreads();
  const int lane = t & 63, w = t >> 6;
  const int v = hist[t];
  int s = v;
#pragma unroll
  for (int o = 1; o < 64; o <<= 1) { int u = __shfl_up(s, o); if (lane >= o) s += u; }
  if (lane == 63) wsum[w] = s;
  __syncthreads();
  int add = 0;
  for (int k = 0; k < w; ++k) add += wsum[k];
  const int ls = add + s - v;
  lstart[t] = ls;
  lcur[t] = ls;
  wbase[t] = (v > 0) ? atomicAdd(&gcur[t], v) : 0;
  __syncthreads();
  for (int i = t; i < cnt; i += 256) {
    const int d = dst[e0 + i], sE = src[e0 + i];
    const int r = atomicAdd(&lcur[d >> BSHIFT], 1);
    sortbuf[r] = ((unsigned)d << 16) | (unsigned)sE;
  }
  __syncthreads();
  for (int i = t; i < cnt; i += 256) {
    const unsigned p = sortbuf[i];
    const int b = (int)(p >> (16 + BSHIFT));
    pbuf[wbase[b] + (i - lstart[b])] = p;
  }
}

// ---------------- k_fill2: per-node offs + edge placement (bucket-local writes) -------------
__global__ __launch_bounds__(256) void k_fill2(
    const unsigned* __restrict__ pbuf, const int* __restrict__ gstart,
    int* __restrict__ offs, int* __restrict__ eidx, int n, int E)
{
  __shared__ int cnt[256], base[256];
  __shared__ int wsum[4];
  const int b = blockIdx.x, t = threadIdx.x;
  const int node0 = b << BSHIFT;
  const int ebeg = gstart[b], eend = gstart[b + 1];
  cnt[t] = 0;
  __syncthreads();
  for (int i = ebeg + t; i < eend; i += 256)
    atomicAdd(&cnt[(pbuf[i] >> 16) & 255], 1);
  __syncthreads();
  const int lane = t & 63, w = t >> 6;
  const int v = cnt[t];
  int s = v;
#pragma unroll
  for (int o = 1; o < 64; o <<= 1) { int u = __shfl_up(s, o); if (lane >= o) s += u; }
  if (lane == 63) wsum[w] = s;
  __syncthreads();
  int add = 0;
  for (int k = 0; k < w; ++k) add += wsum[k];
  base[t] = ebeg + add + s - v;
  if (node0 + t < n) offs[node0 + t] = base[t];
  __syncthreads();
  for (int i = ebeg + t; i < eend; i += 256) {
    const unsigned p = pbuf[i];
    const int pos = atomicAdd(&base[(p >> 16) & 255], 1);
    eidx[pos] = (int)(p & 0xFFFFu);
  }
  if (b == 0 && t == 0) offs[n] = E;
}

// ---------------- Aggregation: one wave per dst node (proven version) -----------------------
__global__ __launch_bounds__(256) void k_aggr(
    const unsigned* __restrict__ xpb, const float* __restrict__ a_s,
    const float* __restrict__ a_d, const int* __restrict__ offs,
    const int* __restrict__ eidx, const float* __restrict__ bias,
    float* __restrict__ out, int n)
{
  const int wid = (blockIdx.x * blockDim.x + threadIdx.x) >> 6;
  const int lane = threadIdx.x & 63;
  if (wid >= n) return;
  const int h = lane >> 4;
  const int sbase = lane & 48;

  const float adh = a_d[wid * HEADS + h];

  float l = a_s[wid * HEADS + h] + adh;
  l = fmaxf(l, 0.2f * l);
  const float pself = __expf(l);
  float den = pself;
  const unsigned uself = xpb[(size_t)wid * 64 + lane];
  float accx = pself * bf_lo(uself), accy = pself * bf_hi(uself);

  const int beg = offs[wid], end = offs[wid + 1];
  int e = beg;
  int nb = (end - beg) >> 2;

#define LOADB(s0, s1, s2, s3, u0, u1, u2, u3, aL)                        \
  {                                                                      \
    s0 = eidx[e]; s1 = eidx[e + 1]; s2 = eidx[e + 2]; s3 = eidx[e + 3];  \
    u0 = xpb[(size_t)s0 * 64 + lane];                                    \
    u1 = xpb[(size_t)s1 * 64 + lane];                                    \
    u2 = xpb[(size_t)s2 * 64 + lane];                                    \
    u3 = xpb[(size_t)s3 * 64 + lane];                                    \
    const int sj = (lane & 2) ? ((lane & 1) ? s3 : s2)                   \
                              : ((lane & 1) ? s1 : s0);                  \
    aL = a_s[sj * HEADS + h];                                            \
  }
#define CONSUME(u0, u1, u2, u3, aL)                                      \
  {                                                                      \
    float lv = aL + adh; lv = fmaxf(lv, 0.2f * lv);                      \
    const float pl = __expf(lv);                                         \
    const float p0 = __shfl(pl, sbase + 0);                              \
    const float p1 = __shfl(pl, sbase + 1);                              \
    const float p2 = __shfl(pl, sbase + 2);                              \
    const float p3 = __shfl(pl, sbase + 3);                              \
    den += p0 + p1 + p2 + p3;                                            \
    accx += p0 * bf_lo(u0) + p1 * bf_lo(u1) + p2 * bf_lo(u2) + p3 * bf_lo(u3); \
    accy += p0 * bf_hi(u0) + p1 * bf_hi(u1) + p2 * bf_hi(u2) + p3 * bf_hi(u3); \
  }

  if (nb > 0) {
    int sa0, sa1, sa2, sa3, sb0, sb1, sb2, sb3;
    unsigned ua0, ua1, ua2, ua3, ub0, ub1, ub2, ub3;
    float aa, ab;
    LOADB(sa0, sa1, sa2, sa3, ua0, ua1, ua2, ua3, aa);
    e += 4;
    --nb;
    while (nb >= 2) {
      LOADB(sb0, sb1, sb2, sb3, ub0, ub1, ub2, ub3, ab);
      e += 4;
      CONSUME(ua0, ua1, ua2, ua3, aa);
      LOADB(sa0, sa1, sa2, sa3, ua0, ua1, ua2, ua3, aa);
      e += 4;
      CONSUME(ub0, ub1, ub2, ub3, ab);
      nb -= 2;
    }
    if (nb == 1) {
      LOADB(sb0, sb1, sb2, sb3, ub0, ub1, ub2, ub3, ab);
      e += 4;
      CONSUME(ua0, ua1, ua2, ua3, aa);
      CONSUME(ub0, ub1, ub2, ub3, ab);
    } else {
      CONSUME(ua0, ua1, ua2, ua3, aa);
    }
  }
  for (; e < end; ++e) {
    const int s = eidx[e];
    const unsigned u = xpb[(size_t)s * 64 + lane];
    float lv = a_s[s * HEADS + h] + adh;
    lv = fmaxf(lv, 0.2f * lv);
    const float p = __expf(lv);
    den += p;
    accx += p * bf_lo(u);
    accy += p * bf_hi(u);
  }
#undef LOADB
#undef CONSUME

  const float2 b2 = ((const float2*)bias)[lane];
  const float inv = 1.f / den;
  float ox = accx * inv + b2.x;
  float oy = accy * inv + b2.y;
  float2 o = make_float2(ox > 0.f ? ox : 0.f, oy > 0.f ? oy : 0.f);
  ((float2*)out)[(size_t)wid * 64 + lane] = o;
}

extern "C" void kernel_launch(void* const* d_in, const int* in_sizes, int n_in,
                              void* d_out, int out_size, void* d_ws, size_t ws_size,
                              hipStream_t stream) {
  const float* x       = (const float*)d_in[0];
  const int*   ei      = (const int*)d_in[1];
  const float* W       = (const float*)d_in[2];
  const float* att_src = (const float*)d_in[3];
  const float* att_dst = (const float*)d_in[4];
  const float* bias    = (const float*)d_in[5];
  float* out = (float*)d_out;
  const int n = in_sizes[0] / 128;
  const int E = in_sizes[1] / 2;
  const int* srce = ei;
  const int* dste = ei + E;

  char* ws = (char*)d_ws;
  size_t o = 0;
  unsigned* xpb = (unsigned*)(ws + o); o += (size_t)n * 128 * 2;  // bf16 xp
  o = (o + 255) & ~(size_t)255;
  float* a_s = (float*)(ws + o); o += (size_t)n * HEADS * 4;
  float* a_d = (float*)(ws + o); o += (size_t)n * HEADS * 4;
  unsigned short* Wtb = (unsigned short*)(ws + o); o += 128 * 128 * 2;
  int* ghist  = (int*)(ws + o);  o += 256 * 4;
  int* gstart = (int*)(ws + o);  o += 260 * 4;
  int* gcur   = (int*)(ws + o);  o += 256 * 4;
  int* done   = (int*)(ws + o);  o += 4 * 4;
  int* offs   = (int*)(ws + o);  o += (size_t)(n + 4) * 4;
  int* eidx   = (int*)(ws + o);  o += (size_t)E * 4;
  unsigned* pbuf = (unsigned*)(ws + o); o += (size_t)E * 4;

  const int GB  = (n + 63) / 64;          // GEMM blocks
  const int NHB = (E + 4095) / 4096;      // hist blocks
  const int NB  = (n + 255) >> BSHIFT;    // buckets
  k_wprep<<<64, 256, 0, stream>>>(W, Wtb, ghist, done);
  k_mega<<<GB + NHB, 256, 0, stream>>>(x, Wtb, att_src, att_dst, xpb, a_s, a_d,
                                       dste, ghist, gstart, gcur, done, n, E, GB, NHB);
  k_part<<<(E + 4095) / 4096, 256, 0, stream>>>(srce, dste, gcur, pbuf, E);
  k_fill2<<<NB, 256, 0, stream>>>(pbuf, gstart, offs, eidx, n, E);
  k_aggr<<<(n + 3) / 4, 256, 0, stream>>>(xpb, a_s, a_d, offs, eidx, bias, out, n);
}